// Round 10
// baseline (273.674 us; speedup 1.0000x reference)
//
#include <hip/hip_runtime.h>

#define FD 128      // feature dim (both layers)
#define BSH 7       // log2(nodes per bucket) = 128 nodes/bucket
#define CH 4096     // edges per partition block (391 blocks)
#define CHT 16      // edges per thread (CH / 256)
#define KMAX 512    // max buckets
#define SCAP 8192   // build_kernel LDS edge stage (mean bucket = 4092, max ~4400)
#define NCH 8       // src chunk planes (chunk = src >> CSH); requires N <= 57344
#define CSH 13      // 8192 nodes/chunk -> 2 MB of h' per chunk (per-XCD L2-resident)
// packed pair: (local_dst << 17) | src   -- requires N <= 131072

typedef __attribute__((ext_vector_type(8))) short bf16x8;
typedef __attribute__((ext_vector_type(4))) float f32x4;

__device__ inline unsigned bfr(float f) {   // fp32 -> bf16 bits, round-nearest-even
    unsigned u = __float_as_uint(f);
    return (u + 0x7FFF + ((u >> 16) & 1)) >> 16;
}
__device__ inline float uplo(unsigned p) { return __uint_as_float(p << 16); }
__device__ inline float uphi(unsigned p) { return __uint_as_float(p & 0xFFFF0000u); }

// ---------------- CSR build ----------------
// R10: discriminating experiment = R13's chunk-major CSR (rpc[p][v], fetch
// ~80-90 MB, verified) + R9's full-row group gathers (verified). If agg time
// follows fetch -> fabric-bound confirmed; if not -> L2 line-throughput floor.

__global__ __launch_bounds__(256) void partition_kernel(
        const int* __restrict__ src, const int* __restrict__ dst,
        int* __restrict__ lstartG, int* __restrict__ total,
        int* __restrict__ pairs, int E, int K) {
    __shared__ int lcnt[KMAX];     // counts, then scatter cursor
    __shared__ int lstart[KMAX];   // local exclusive prefix
    __shared__ int sm[256];
    __shared__ int staged[CH];
    int t = threadIdx.x;
    int base = blockIdx.x * CH;
    int n = min(CH, E - base);

    lcnt[t] = 0; lcnt[t + 256] = 0;
    __syncthreads();

    int pk[CHT]; int bn[CHT];
    #pragma unroll
    for (int j = 0; j < CHT; ++j) {
        int i = t + j * 256;
        bn[j] = -1;
        if (i < n) {
            int d = dst[base + i];
            int s = src[base + i];
            bn[j] = d >> BSH;
            pk[j] = ((d & ((1 << BSH) - 1)) << 17) | s;
            atomicAdd(&lcnt[bn[j]], 1);
        }
    }
    __syncthreads();

    // exclusive scan of 512 bins, 2 consecutive bins per thread
    int c0 = lcnt[2 * t], c1 = lcnt[2 * t + 1];
    int s2 = c0 + c1;
    sm[t] = s2;
    __syncthreads();
    for (int off = 1; off < 256; off <<= 1) {
        int add = (t >= off) ? sm[t - off] : 0;
        __syncthreads();
        sm[t] += add;
        __syncthreads();
    }
    int ex = sm[t] - s2;
    lstart[2 * t] = ex;     lstart[2 * t + 1] = ex + c0;
    lcnt[2 * t]   = ex;     lcnt[2 * t + 1]   = ex + c0;   // cursor
    __syncthreads();

    // scatter chunk into staged[], sorted by bucket
    #pragma unroll
    for (int j = 0; j < CHT; ++j) {
        if (bn[j] >= 0) {
            int pos = atomicAdd(&lcnt[bn[j]], 1);
            staged[pos] = pk[j];
        }
    }
    __syncthreads();

    // sequential coalesced copy-out: this block owns pairs[base .. base+n)
    for (int i = t; i < n; i += 256)
        pairs[base + i] = staged[i];

    // per-block bucket boundaries + bucket totals
    size_t lrow = (size_t)blockIdx.x * (K + 1);
    for (int b = t; b < K; b += 256) {
        lstartG[lrow + b] = lstart[b];
        int c = lcnt[b] - lstart[b];
        if (c) atomicAdd(&total[b], c);
    }
    if (t == 0) lstartG[lrow + K] = n;
}

// exclusive scan of K bucket totals -> bbase
__global__ __launch_bounds__(512) void totscan_kernel(
        const int* __restrict__ total, int* __restrict__ bbase, int K, int E) {
    __shared__ int sm[512];
    int t = threadIdx.x;
    int v = (t < K) ? total[t] : 0;
    sm[t] = v;
    __syncthreads();
    for (int off = 1; off < 512; off <<= 1) {
        int add = (t >= off) ? sm[t - off] : 0;
        __syncthreads();
        sm[t] += add;
        __syncthreads();
    }
    if (t < K) bbase[t] = sm[t] - v;
    if (t == 0) bbase[K] = E;
}

// transpose A[R][C] -> B[C][R]  (lstartG [PB][K+1] -> lstartT [K+1][PB])
__global__ __launch_bounds__(256) void tr_kernel(
        const int* __restrict__ A, int* __restrict__ B, int R, int C) {
    __shared__ int tile[32][33];
    int c0 = blockIdx.x * 32, r0 = blockIdx.y * 32;
    int tx = threadIdx.x, ty = threadIdx.y;   // block (32, 8)
    for (int i = ty; i < 32; i += 8) {
        int r = r0 + i, c = c0 + tx;
        if (r < R && c < C) tile[i][tx] = A[(size_t)r * C + c];
    }
    __syncthreads();
    for (int i = ty; i < 32; i += 8) {
        int c = c0 + i, r = r0 + tx;
        if (c < C && r < R) B[(size_t)c * R + r] = tile[tx][i];
    }
}

// Per-bucket: gather fragments into LDS, bin per (row, src-chunk) (1024 bins,
// key=(row<<3)|chunk), scan, write dis/rpc, scatter col in (row,chunk) order.
// R13-verified structure; descriptors from transposed lstart (nf <= 2).
__global__ __launch_bounds__(256) void build_kernel(
        const int* __restrict__ pairs, const int* __restrict__ lstartT,
        const int* __restrict__ bbase, int* __restrict__ rpc,
        float* __restrict__ dis, int* __restrict__ col,
        int N, int PB, int K) {
    __shared__ int staged[SCAP];
    __shared__ int lcnt[128 * NCH];   // counts, then absolute scatter cursor
    __shared__ int pref[128 * NCH];   // bucket-local exclusive prefix
    __shared__ int sm[256];
    int b = blockIdx.x;
    int t = threadIdx.x;
    int nbase = b << BSH;
    int nn = min(1 << BSH, N - nbase);
    int beg = bbase[b];
    int cnt = bbase[b + 1] - beg;

    // fragment descriptors (coalesced reads from transposed lstart; nf <= 2)
    int fp[2], fl0[2], flen[2];
    int nf = 0, mysum = 0;
    for (int p = t; p < PB; p += 256) {
        int l0 = lstartT[(size_t)b * PB + p];
        int l1 = lstartT[(size_t)(b + 1) * PB + p];
        fp[nf] = p; fl0[nf] = l0; flen[nf] = l1 - l0;
        mysum += l1 - l0;
        ++nf;
    }
    // exclusive scan of per-thread sums -> dest offsets in staged
    sm[t] = mysum;
    __syncthreads();
    for (int off = 1; off < 256; off <<= 1) {
        int add = (t >= off) ? sm[t - off] : 0;
        __syncthreads();
        sm[t] += add;
        __syncthreads();
    }
    int o = sm[t] - mysum;

    lcnt[t] = 0; lcnt[t + 256] = 0; lcnt[t + 512] = 0; lcnt[t + 768] = 0;

    if (cnt <= SCAP) {   // fast path (always, for Poisson buckets)
        for (int f = 0; f < nf; ++f) {
            int gbase = fp[f] * CH + fl0[f];
            for (int i = 0; i < flen[f]; ++i) staged[o + i] = pairs[gbase + i];
            o += flen[f];
        }
        __syncthreads();
        for (int i = t; i < cnt; i += 256) {
            int p = staged[i];
            atomicAdd(&lcnt[((p >> 17) << 3) | ((p & 0x1FFFF) >> CSH)], 1);
        }
    } else {             // overflow fallback: count directly from global
        __syncthreads();
        for (int f = 0; f < nf; ++f) {
            int gbase = fp[f] * CH + fl0[f];
            for (int i = 0; i < flen[f]; ++i) {
                int p = pairs[gbase + i];
                atomicAdd(&lcnt[((p >> 17) << 3) | ((p & 0x1FFFF) >> CSH)], 1);
            }
        }
    }
    __syncthreads();

    // exclusive scan of 1024 bins, 4 consecutive per thread
    int b0 = 4 * t;
    int c0 = lcnt[b0], c1 = lcnt[b0 + 1], c2 = lcnt[b0 + 2], c3 = lcnt[b0 + 3];
    int s4 = c0 + c1 + c2 + c3;
    sm[t] = s4;
    __syncthreads();
    for (int off = 1; off < 256; off <<= 1) {
        int add = (t >= off) ? sm[t - off] : 0;
        __syncthreads();
        sm[t] += add;
        __syncthreads();
    }
    int ex = sm[t] - s4;
    pref[b0] = ex; pref[b0 + 1] = ex + c0;
    pref[b0 + 2] = ex + c0 + c1; pref[b0 + 3] = ex + c0 + c1 + c2;
    __syncthreads();

    // dis (row totals) + rpc (per-chunk row starts, planes 0..7;
    // plane 7 == row end since chunk 7 is empty for N <= 57344)
    if (t < 128 && t < nn) {
        int rs = pref[t << 3];
        int re = (t < 127) ? pref[(t + 1) << 3] : cnt;
        dis[nbase + t] = rsqrtf((float)(re - rs + 1));  // deg incl. self-loop
    }
    #pragma unroll
    for (int j = 0; j < 4; ++j) {
        int bin = b0 + j;
        int row = bin >> 3, p = bin & (NCH - 1);
        if (row < nn) rpc[(size_t)p * N + nbase + row] = beg + pref[bin];
    }
    __syncthreads();
    lcnt[b0]     = beg + pref[b0];
    lcnt[b0 + 1] = beg + pref[b0 + 1];
    lcnt[b0 + 2] = beg + pref[b0 + 2];
    lcnt[b0 + 3] = beg + pref[b0 + 3];
    __syncthreads();

    if (cnt <= SCAP) {
        for (int i = t; i < cnt; i += 256) {
            int p = staged[i];
            int key = ((p >> 17) << 3) | ((p & 0x1FFFF) >> CSH);
            int pos = atomicAdd(&lcnt[key], 1);
            col[pos] = p & 0x1FFFF;
        }
    } else {
        for (int f = 0; f < nf; ++f) {
            int gbase = fp[f] * CH + fl0[f];
            for (int i = 0; i < flen[f]; ++i) {
                int p = pairs[gbase + i];
                int key = ((p >> 17) << 3) | ((p & 0x1FFFF) >> CSH);
                int pos = atomicAdd(&lcnt[key], 1);
                col[pos] = p & 0x1FFFF;
            }
        }
    }
}

// ---------------- precision prep ----------------

__global__ void wt_kernel(const float* __restrict__ W1, unsigned short* __restrict__ W1T,
                          const float* __restrict__ W2, unsigned short* __restrict__ W2T) {
    int k = blockIdx.x & (FD - 1);
    int n = threadIdx.x;
    if (blockIdx.x < FD) W1T[n * FD + k] = (unsigned short)bfr(W1[k * FD + n]);
    else                 W2T[n * FD + k] = (unsigned short)bfr(W2[k * FD + n]);
}

// ---------------- MFMA bf16 GEMM: C = bf16( dis[row] * (A @ W) ) ----------------
// R7-proven lean variant: only B staged in LDS; A fragments loaded directly
// from global (lane l16 = row, quad = k-octet -> clean 64 B sectors).

#define APAD 8
#define ASTR (FD + APAD)

template <bool A32>
__device__ void gemm_body(const void* __restrict__ Ap,
                          const unsigned short* __restrict__ WT,
                          const float* __restrict__ dis,
                          unsigned short* __restrict__ C, int M) {
    __shared__ unsigned short Bs[128 * ASTR];
    int tid = threadIdx.x;
    int lane = tid & 63;
    int wave = tid >> 6;
    int quad = lane >> 4;
    int l16 = lane & 15;
    int rowBase = blockIdx.x * 128;

    #pragma unroll
    for (int p = 0; p < 8; ++p) {
        int r = p * 16 + (tid >> 4);
        int cq = (tid & 15) * 8;
        *(uint4*)&Bs[r * ASTR + cq] = *(const uint4*)&WT[(size_t)r * FD + cq];
    }
    __syncthreads();

    int m0 = wave * 32;
    int r0 = rowBase + m0 + l16;        // a0 fragment row
    int r1 = r0 + 16;                   // a1 fragment row
    f32x4 acc[2][8] = {};
    #pragma unroll
    for (int kt = 0; kt < 4; ++kt) {
        int ko = kt * 32 + quad * 8;
        uint4 va = make_uint4(0u, 0u, 0u, 0u);
        uint4 vb = make_uint4(0u, 0u, 0u, 0u);
        if (A32) {
            const float* A = (const float*)Ap;
            if (r0 < M) {
                const float* a = A + (size_t)r0 * FD + ko;
                float4 f0 = *(const float4*)a;
                float4 f1 = *(const float4*)(a + 4);
                va.x = bfr(f0.x) | (bfr(f0.y) << 16);
                va.y = bfr(f0.z) | (bfr(f0.w) << 16);
                va.z = bfr(f1.x) | (bfr(f1.y) << 16);
                va.w = bfr(f1.z) | (bfr(f1.w) << 16);
            }
            if (r1 < M) {
                const float* a = A + (size_t)r1 * FD + ko;
                float4 f0 = *(const float4*)a;
                float4 f1 = *(const float4*)(a + 4);
                vb.x = bfr(f0.x) | (bfr(f0.y) << 16);
                vb.y = bfr(f0.z) | (bfr(f0.w) << 16);
                vb.z = bfr(f1.x) | (bfr(f1.y) << 16);
                vb.w = bfr(f1.z) | (bfr(f1.w) << 16);
            }
        } else {
            const unsigned short* A = (const unsigned short*)Ap;
            if (r0 < M) va = *(const uint4*)(A + (size_t)r0 * FD + ko);
            if (r1 < M) vb = *(const uint4*)(A + (size_t)r1 * FD + ko);
        }
        bf16x8 a0 = *(bf16x8*)&va;
        bf16x8 a1 = *(bf16x8*)&vb;
        #pragma unroll
        for (int n = 0; n < 8; ++n) {
            bf16x8 b = *(bf16x8*)&Bs[(n * 16 + l16) * ASTR + ko];
            acc[0][n] = __builtin_amdgcn_mfma_f32_16x16x32_bf16(a0, b, acc[0][n], 0, 0, 0);
            acc[1][n] = __builtin_amdgcn_mfma_f32_16x16x32_bf16(a1, b, acc[1][n], 0, 0, 0);
        }
    }

    #pragma unroll
    for (int ms = 0; ms < 2; ++ms) {
        #pragma unroll
        for (int r = 0; r < 4; ++r) {
            int grow = rowBase + m0 + ms * 16 + quad * 4 + r;
            if (grow < M) {
                float dv = dis[grow];
                #pragma unroll
                for (int n = 0; n < 8; ++n) {
                    C[(size_t)grow * FD + n * 16 + l16] =
                        (unsigned short)bfr(dv * acc[ms][n][r]);
                }
            }
        }
    }
}

__global__ __launch_bounds__(256) void gemm_mfma_f32(
        const float* __restrict__ A, const unsigned short* __restrict__ WT,
        const float* __restrict__ dis, unsigned short* __restrict__ C, int M) {
    gemm_body<true>(A, WT, dis, C, M);
}

__global__ __launch_bounds__(256) void gemm_mfma_bf16(
        const unsigned short* __restrict__ A, const unsigned short* __restrict__ WT,
        const float* __restrict__ dis, unsigned short* __restrict__ C, int M) {
    gemm_body<false>(A, WT, dis, C, M);
}

// ---------------- CSR aggregation + bias + ReLU ----------------
// R10: chunk sweep + full-row group gathers. Wave = 4 nodes (one per 16-lane
// group). Per chunk p, group g walks its node's segment [rpc[p][v], rpc[p+1][v])
// batched 8-deep: 8 col loads -> 8 predicated 256 B row gathers (dwordx4,
// 16 lanes x 16 B; up to 32 edges / 8 KB in flight per wave) -> unrolled
// accumulate. Lane r of a group holds features 8r..8r+7; no cross-group
// combine (each group owns its node). All waves sweep chunk p together ->
// gather window ~2 MB / XCD L2. Epilogue: each group writes its node's row.

__global__ __launch_bounds__(256) void agg_kernel(
        const unsigned* __restrict__ h, const float* __restrict__ dis,
        const int* __restrict__ rpc, const int* __restrict__ col,
        const float2* __restrict__ bias, void* __restrict__ out,
        int N, int E, int obf) {
    int w4 = __builtin_amdgcn_readfirstlane(blockIdx.x * 4 + threadIdx.y);
    int v0 = w4 * 4;
    if (v0 >= N) return;
    int t = threadIdx.x;                    // 0..63
    int g = t >> 4;                         // group = node slot 0..3
    int r = t & 15;                         // lane in group; features 8r..8r+7
    int vg = v0 + g;
    int vv = min(vg, N - 1);
    bool alive = (vg < N);

    const float* bf = (const float*)bias;
    float4 bb0 = *(const float4*)(bf + 8 * r);
    float4 bb1 = *(const float4*)(bf + 8 * r + 4);

    float acc[8] = {0.f, 0.f, 0.f, 0.f, 0.f, 0.f, 0.f, 0.f};

    for (int p = 0; p < NCH - 1; ++p) {     // chunks 0..6 (7 empty, N<=57344)
        int st = rpc[(size_t)p * N + vv];
        int en = rpc[(size_t)(p + 1) * N + vv];
        int len = alive ? (en - st) : 0;
        int ml = len;
        ml = max(ml, __shfl_xor(ml, 16, 64));
        ml = max(ml, __shfl_xor(ml, 32, 64));

        for (int j0 = 0; j0 < ml; j0 += 8) {
            int c[8];
            #pragma unroll
            for (int jj = 0; jj < 8; ++jj)
                c[jj] = col[min(st + j0 + jj, E - 1)];   // clamped, in-bounds
            uint4 q[8];
            #pragma unroll
            for (int jj = 0; jj < 8; ++jj)
                if (j0 + jj < len)
                    q[jj] = *(const uint4*)(h + (size_t)c[jj] * 64 + r * 4);
            #pragma unroll
            for (int jj = 0; jj < 8; ++jj)
                if (j0 + jj < len) {
                    acc[0] += uplo(q[jj].x); acc[1] += uphi(q[jj].x);
                    acc[2] += uplo(q[jj].y); acc[3] += uphi(q[jj].y);
                    acc[4] += uplo(q[jj].z); acc[5] += uphi(q[jj].z);
                    acc[6] += uplo(q[jj].w); acc[7] += uphi(q[jj].w);
                }
        }
    }

    // self term + bias + relu; group g writes its own node's row
    float dv = dis[vv];
    uint4 hq = *(const uint4*)(h + (size_t)vv * 64 + r * 4);
    acc[0] += uplo(hq.x); acc[1] += uphi(hq.x);
    acc[2] += uplo(hq.y); acc[3] += uphi(hq.y);
    acc[4] += uplo(hq.z); acc[5] += uphi(hq.z);
    acc[6] += uplo(hq.w); acc[7] += uphi(hq.w);
    float o0 = fmaxf(fmaf(dv, acc[0], bb0.x), 0.0f);
    float o1 = fmaxf(fmaf(dv, acc[1], bb0.y), 0.0f);
    float o2 = fmaxf(fmaf(dv, acc[2], bb0.z), 0.0f);
    float o3 = fmaxf(fmaf(dv, acc[3], bb0.w), 0.0f);
    float o4 = fmaxf(fmaf(dv, acc[4], bb1.x), 0.0f);
    float o5 = fmaxf(fmaf(dv, acc[5], bb1.y), 0.0f);
    float o6 = fmaxf(fmaf(dv, acc[6], bb1.z), 0.0f);
    float o7 = fmaxf(fmaf(dv, acc[7], bb1.w), 0.0f);

    if (alive) {
        if (obf) {
            uint4 ov;
            ov.x = bfr(o0) | (bfr(o1) << 16);
            ov.y = bfr(o2) | (bfr(o3) << 16);
            ov.z = bfr(o4) | (bfr(o5) << 16);
            ov.w = bfr(o6) | (bfr(o7) << 16);
            *(uint4*)((unsigned*)out + (size_t)vg * 64 + r * 4) = ov;
        } else {
            float* fo = (float*)out + (size_t)vg * 128 + r * 8;
            *(float4*)fo = make_float4(o0, o1, o2, o3);
            *(float4*)(fo + 4) = make_float4(o4, o5, o6, o7);
        }
    }
}

// ---------------- launch ----------------

extern "C" void kernel_launch(void* const* d_in, const int* in_sizes, int n_in,
                              void* d_out, int out_size, void* d_ws, size_t ws_size,
                              hipStream_t stream) {
    const float* x  = (const float*)d_in[0];
    const int*   ei = (const int*)d_in[1];   // [2, E] int32
    const float* W1 = (const float*)d_in[2];
    const float* b1 = (const float*)d_in[3];
    const float* W2 = (const float*)d_in[4];
    const float* b2 = (const float*)d_in[5];

    int N = in_sizes[0] / FD;
    int E = in_sizes[1] / 2;
    const int* src = ei;
    const int* dst = ei + E;
    int K = (N + (1 << BSH) - 1) >> BSH;     // buckets (<= 512 assumed)
    int PB = (E + CH - 1) / CH;              // partition blocks

    char* base = (char*)d_ws;
    size_t off = 0;
    auto align256 = [](size_t v) { return (v + 255) & ~(size_t)255; };
    float*          dis   = (float*)(base + off);          off += align256((size_t)N * 4);
    int*            total = (int*)(base + off);            off += align256(512 * 4);
    int*            bbase = (int*)(base + off);            off += align256(513 * 4);
    unsigned short* w1t   = (unsigned short*)(base + off); off += align256((size_t)FD * FD * 2);
    unsigned short* w2t   = (unsigned short*)(base + off); off += align256((size_t)FD * FD * 2);
    int*            col   = (int*)(base + off);            off += align256((size_t)E * 4);
    unsigned short* hbuf  = (unsigned short*)(base + off); off += align256((size_t)N * FD * 2);
    unsigned short* z1    = (unsigned short*)(base + off); off += align256((size_t)N * FD * 2);
    int*            pairs = (int*)(base + off);            off += align256((size_t)E * 4);
    int*            rpc   = (int*)(base + off);            off += align256((size_t)NCH * N * 4);
    int*            lstartG = (int*)hbuf;   // overlay: dead until gemm1 writes hbuf
    int*            lstartT = (int*)z1;     // overlay: dead until agg1 writes z1
    (void)ws_size; (void)n_in; (void)out_size;

    (void)hipMemsetAsync(total, 0, 512 * 4, stream);
    partition_kernel<<<PB, 256, 0, stream>>>(src, dst, lstartG, total, pairs, E, K);
    totscan_kernel  <<<1, 512, 0, stream>>>(total, bbase, K, E);
    dim3 trb(32, 8);
    dim3 trg((K + 1 + 31) / 32, (PB + 31) / 32);
    tr_kernel       <<<trg, trb, 0, stream>>>(lstartG, lstartT, PB, K + 1);
    build_kernel    <<<K, 256, 0, stream>>>(pairs, lstartT, bbase, rpc, dis, col, N, PB, K);

    wt_kernel<<<2 * FD, FD, 0, stream>>>(W1, w1t, W2, w2t);

    dim3 aggBlk(64, 4);
    int aggGrid = (N + 15) / 16;             // wave = 4 nodes, block = 16 nodes
    int gemmGrid = (N + 127) / 128;

    gemm_mfma_f32 <<<gemmGrid, 256, 0, stream>>>(x, w1t, dis, hbuf, N);
    agg_kernel<<<aggGrid, aggBlk, 0, stream>>>((const unsigned*)hbuf, dis, rpc, col,
                                               (const float2*)b1, z1, N, E, 1);
    gemm_mfma_bf16<<<gemmGrid, 256, 0, stream>>>(z1, w2t, dis, hbuf, N);
    agg_kernel<<<aggGrid, aggBlk, 0, stream>>>((const unsigned*)hbuf, dis, rpc, col,
                                               (const float2*)b2, d_out, N, E, 0);
}

// Round 11
// 245.446 us; speedup vs baseline: 1.1150x; 1.1150x over previous
//
#include <hip/hip_runtime.h>

#define FD 128      // feature dim (both layers)
#define BSH 7       // log2(nodes per bucket) = 128 nodes/bucket
#define CH 4096     // edges per partition block (391 blocks)
#define CHT 16      // edges per thread (CH / 256)
#define KMAX 512    // max buckets
#define SCAP 8192   // build_kernel LDS edge stage (mean bucket = 4092, max ~4400)
// packed pair: (local_dst << 17) | src   -- requires N <= 131072

typedef __attribute__((ext_vector_type(8))) short bf16x8;
typedef __attribute__((ext_vector_type(4))) float f32x4;

__device__ inline unsigned bfr(float f) {   // fp32 -> bf16 bits, round-nearest-even
    unsigned u = __float_as_uint(f);
    return (u + 0x7FFF + ((u >> 16) & 1)) >> 16;
}
__device__ inline float uplo(unsigned p) { return __uint_as_float(p << 16); }
__device__ inline float uphi(unsigned p) { return __uint_as_float(p & 0xFFFF0000u); }

// ---------------- CSR build ----------------
// R11 = R8 compute (248.4 us champion), dispatch-compressed: totscan folded
// into tr launch (extra block), wt folded into build launch (64 extra
// blocks). agg = round-0 proven floor (48.6 us, invariant across 7 designs).

__global__ __launch_bounds__(256) void partition_kernel(
        const int* __restrict__ src, const int* __restrict__ dst,
        int* __restrict__ lstartG, int* __restrict__ total,
        int* __restrict__ pairs, int E, int K) {
    __shared__ int lcnt[KMAX];     // counts, then scatter cursor
    __shared__ int lstart[KMAX];   // local exclusive prefix
    __shared__ int sm[256];
    __shared__ int staged[CH];
    int t = threadIdx.x;
    int base = blockIdx.x * CH;
    int n = min(CH, E - base);

    lcnt[t] = 0; lcnt[t + 256] = 0;
    __syncthreads();

    int pk[CHT]; int bn[CHT];
    #pragma unroll
    for (int j = 0; j < CHT; ++j) {
        int i = t + j * 256;
        bn[j] = -1;
        if (i < n) {
            int d = dst[base + i];
            int s = src[base + i];
            bn[j] = d >> BSH;
            pk[j] = ((d & ((1 << BSH) - 1)) << 17) | s;
            atomicAdd(&lcnt[bn[j]], 1);
        }
    }
    __syncthreads();

    // exclusive scan of 512 bins, 2 consecutive bins per thread
    int c0 = lcnt[2 * t], c1 = lcnt[2 * t + 1];
    int s2 = c0 + c1;
    sm[t] = s2;
    __syncthreads();
    for (int off = 1; off < 256; off <<= 1) {
        int add = (t >= off) ? sm[t - off] : 0;
        __syncthreads();
        sm[t] += add;
        __syncthreads();
    }
    int ex = sm[t] - s2;
    lstart[2 * t] = ex;     lstart[2 * t + 1] = ex + c0;
    lcnt[2 * t]   = ex;     lcnt[2 * t + 1]   = ex + c0;   // cursor
    __syncthreads();

    // scatter chunk into staged[], sorted by bucket
    #pragma unroll
    for (int j = 0; j < CHT; ++j) {
        if (bn[j] >= 0) {
            int pos = atomicAdd(&lcnt[bn[j]], 1);
            staged[pos] = pk[j];
        }
    }
    __syncthreads();

    // sequential coalesced copy-out: this block owns pairs[base .. base+n)
    for (int i = t; i < n; i += 256)
        pairs[base + i] = staged[i];

    // per-block bucket boundaries + bucket totals
    size_t lrow = (size_t)blockIdx.x * (K + 1);
    for (int b = t; b < K; b += 256) {
        lstartG[lrow + b] = lstart[b];
        int c = lcnt[b] - lstart[b];
        if (c) atomicAdd(&total[b], c);
    }
    if (t == 0) lstartG[lrow + K] = n;
}

// merged: blocks [0, nbx*nby) transpose lstartG [PB][K+1] -> lstartT [K+1][PB];
// last block does the 512-wide exclusive scan of total -> bbase (+ rp[N]=E).
__global__ __launch_bounds__(512) void trtot_kernel(
        const int* __restrict__ A, int* __restrict__ B, int R, int C,
        const int* __restrict__ total, int* __restrict__ bbase,
        int* __restrict__ rp, int K, int E, int N, int nbx) {
    __shared__ int tile[32][33];
    int t = threadIdx.x;
    if ((int)blockIdx.x == gridDim.x - 1) {      // totscan body
        __shared__ int sm[512];
        int v = (t < K) ? total[t] : 0;
        sm[t] = v;
        __syncthreads();
        for (int off = 1; off < 512; off <<= 1) {
            int add = (t >= off) ? sm[t - off] : 0;
            __syncthreads();
            sm[t] += add;
            __syncthreads();
        }
        if (t < K) bbase[t] = sm[t] - v;
        if (t == 0) { bbase[K] = E; rp[N] = E; }
        return;
    }
    int c0 = (blockIdx.x % nbx) * 32, r0 = (blockIdx.x / nbx) * 32;
    int tx = t & 31, ty = t >> 5;                // 512 threads: ty in [0,16)
    for (int i = ty; i < 32; i += 16) {
        int r = r0 + i, c = c0 + tx;
        if (r < R && c < C) tile[i][tx] = A[(size_t)r * C + c];
    }
    __syncthreads();
    for (int i = ty; i < 32; i += 16) {
        int c = c0 + i, r = r0 + tx;
        if (c < C && r < R) B[(size_t)c * R + r] = tile[tx][i];
    }
}

// Per-bucket (blocks < K): stage fragments into LDS with FUSED per-wave bin
// count, 512-entry scan ([bin][wave] bin-major), then scatter with per-wave
// cursors. Blocks >= K: weight transpose fp32->bf16 (wt fold, 64 blocks).
__global__ __launch_bounds__(256) void build_kernel(
        const int* __restrict__ pairs, const int* __restrict__ lstartT,
        const int* __restrict__ bbase, int* __restrict__ rp,
        float* __restrict__ dis, int* __restrict__ col, int N, int PB, int K,
        const float* __restrict__ W1, unsigned short* __restrict__ W1T,
        const float* __restrict__ W2, unsigned short* __restrict__ W2T) {
    __shared__ int staged[SCAP];
    __shared__ int lcnt[512];    // [bin*4+wave] counts, then absolute cursor
    __shared__ int pref[512];    // exclusive prefix (bucket-local)
    __shared__ int sm[256];
    int b = blockIdx.x;
    int t = threadIdx.x;

    if (b >= K) {                // wt fold: 64 blocks, 2 elems/thread
        int bb = b - K;
        #pragma unroll
        for (int rr = 0; rr < 2; ++rr) {
            int f = bb * 512 + rr * 256 + t;     // flat over 2*FD*FD = 32768
            int w = f >> 14, rm = f & 16383, k = rm >> 7, nn2 = rm & 127;
            const float* W = w ? W2 : W1;
            unsigned short* WT = w ? W2T : W1T;
            WT[nn2 * FD + k] = (unsigned short)bfr(W[k * FD + nn2]);
        }
        return;
    }

    int wv = t >> 6;
    int nbase = b << BSH;
    int nn = min(1 << BSH, N - nbase);
    int beg = bbase[b];
    int cnt = bbase[b + 1] - beg;

    // fragment descriptors (coalesced reads from transposed lstart; nf <= 2)
    int fp[2], fl0[2], flen[2];
    int nf = 0, mysum = 0;
    for (int p = t; p < PB; p += 256) {
        int l0 = lstartT[(size_t)b * PB + p];
        int l1 = lstartT[(size_t)(b + 1) * PB + p];
        fp[nf] = p; fl0[nf] = l0; flen[nf] = l1 - l0;
        mysum += l1 - l0;
        ++nf;
    }
    // exclusive scan of per-thread sums -> dest offsets in staged
    sm[t] = mysum;
    __syncthreads();
    for (int off = 1; off < 256; off <<= 1) {
        int add = (t >= off) ? sm[t - off] : 0;
        __syncthreads();
        sm[t] += add;
        __syncthreads();
    }
    int o = sm[t] - mysum;

    lcnt[t] = 0; lcnt[t + 256] = 0;
    __syncthreads();

    if (cnt <= SCAP) {   // fast path (always, for Poisson buckets)
        int oo = o;
        for (int f = 0; f < nf; ++f) {
            int gbase = fp[f] * CH + fl0[f];
            for (int i = 0; i < flen[f]; ++i) {
                int p = pairs[gbase + i];
                staged[oo + i] = p;
                atomicAdd(&lcnt[((p >> 17) << 2) | wv], 1);   // fused count
            }
            oo += flen[f];
        }
    } else {             // overflow fallback: count directly from global
        for (int f = 0; f < nf; ++f) {
            int gbase = fp[f] * CH + fl0[f];
            for (int i = 0; i < flen[f]; ++i)
                atomicAdd(&lcnt[((pairs[gbase + i] >> 17) << 2) | wv], 1);
        }
    }
    __syncthreads();

    // exclusive scan of 512 entries (bin-major: bin*4+wave), 2 per thread
    int c0 = lcnt[2 * t], c1 = lcnt[2 * t + 1];
    int s2 = c0 + c1;
    sm[t] = s2;
    __syncthreads();
    for (int off = 1; off < 256; off <<= 1) {
        int add = (t >= off) ? sm[t - off] : 0;
        __syncthreads();
        sm[t] += add;
        __syncthreads();
    }
    int ex = sm[t] - s2;
    pref[2 * t] = ex;  pref[2 * t + 1] = ex + c0;
    __syncthreads();

    // rp/dis per row (row start = plane-0 prefix; deg = row-range length)
    if (t < 128 && t < nn) {
        int rs = pref[t << 2];
        int re = (t < 127) ? pref[(t + 1) << 2] : cnt;
        rp[nbase + t] = beg + rs;
        dis[nbase + t] = rsqrtf((float)(re - rs + 1));  // deg incl. self-loop
    }
    // cursors (absolute)
    lcnt[2 * t]     = beg + pref[2 * t];
    lcnt[2 * t + 1] = beg + pref[2 * t + 1];
    __syncthreads();

    if (cnt <= SCAP) {
        int oo = o;
        for (int f = 0; f < nf; ++f) {
            for (int i = 0; i < flen[f]; ++i) {
                int p = staged[oo + i];
                int pos = atomicAdd(&lcnt[((p >> 17) << 2) | wv], 1);
                col[pos] = p & 0x1FFFF;
            }
            oo += flen[f];
        }
    } else {
        for (int f = 0; f < nf; ++f) {
            int gbase = fp[f] * CH + fl0[f];
            for (int i = 0; i < flen[f]; ++i) {
                int p = pairs[gbase + i];
                int pos = atomicAdd(&lcnt[((p >> 17) << 2) | wv], 1);
                col[pos] = p & 0x1FFFF;
            }
        }
    }
}

// ---------------- MFMA bf16 GEMM: C = bf16( dis[row] * (A @ W) ) ----------------
// R7-proven lean variant: only B staged in LDS; A fragments loaded directly
// from global (lane l16 = row, quad = k-octet -> clean 64 B sectors).

#define APAD 8
#define ASTR (FD + APAD)

template <bool A32>
__device__ void gemm_body(const void* __restrict__ Ap,
                          const unsigned short* __restrict__ WT,
                          const float* __restrict__ dis,
                          unsigned short* __restrict__ C, int M) {
    __shared__ unsigned short Bs[128 * ASTR];
    int tid = threadIdx.x;
    int lane = tid & 63;
    int wave = tid >> 6;
    int quad = lane >> 4;
    int l16 = lane & 15;
    int rowBase = blockIdx.x * 128;

    #pragma unroll
    for (int p = 0; p < 8; ++p) {
        int r = p * 16 + (tid >> 4);
        int cq = (tid & 15) * 8;
        *(uint4*)&Bs[r * ASTR + cq] = *(const uint4*)&WT[(size_t)r * FD + cq];
    }
    __syncthreads();

    int m0 = wave * 32;
    int r0 = rowBase + m0 + l16;        // a0 fragment row
    int r1 = r0 + 16;                   // a1 fragment row
    f32x4 acc[2][8] = {};
    #pragma unroll
    for (int kt = 0; kt < 4; ++kt) {
        int ko = kt * 32 + quad * 8;
        uint4 va = make_uint4(0u, 0u, 0u, 0u);
        uint4 vb = make_uint4(0u, 0u, 0u, 0u);
        if (A32) {
            const float* A = (const float*)Ap;
            if (r0 < M) {
                const float* a = A + (size_t)r0 * FD + ko;
                float4 f0 = *(const float4*)a;
                float4 f1 = *(const float4*)(a + 4);
                va.x = bfr(f0.x) | (bfr(f0.y) << 16);
                va.y = bfr(f0.z) | (bfr(f0.w) << 16);
                va.z = bfr(f1.x) | (bfr(f1.y) << 16);
                va.w = bfr(f1.z) | (bfr(f1.w) << 16);
            }
            if (r1 < M) {
                const float* a = A + (size_t)r1 * FD + ko;
                float4 f0 = *(const float4*)a;
                float4 f1 = *(const float4*)(a + 4);
                vb.x = bfr(f0.x) | (bfr(f0.y) << 16);
                vb.y = bfr(f0.z) | (bfr(f0.w) << 16);
                vb.z = bfr(f1.x) | (bfr(f1.y) << 16);
                vb.w = bfr(f1.z) | (bfr(f1.w) << 16);
            }
        } else {
            const unsigned short* A = (const unsigned short*)Ap;
            if (r0 < M) va = *(const uint4*)(A + (size_t)r0 * FD + ko);
            if (r1 < M) vb = *(const uint4*)(A + (size_t)r1 * FD + ko);
        }
        bf16x8 a0 = *(bf16x8*)&va;
        bf16x8 a1 = *(bf16x8*)&vb;
        #pragma unroll
        for (int n = 0; n < 8; ++n) {
            bf16x8 b = *(bf16x8*)&Bs[(n * 16 + l16) * ASTR + ko];
            acc[0][n] = __builtin_amdgcn_mfma_f32_16x16x32_bf16(a0, b, acc[0][n], 0, 0, 0);
            acc[1][n] = __builtin_amdgcn_mfma_f32_16x16x32_bf16(a1, b, acc[1][n], 0, 0, 0);
        }
    }

    #pragma unroll
    for (int ms = 0; ms < 2; ++ms) {
        #pragma unroll
        for (int r = 0; r < 4; ++r) {
            int grow = rowBase + m0 + ms * 16 + quad * 4 + r;
            if (grow < M) {
                float dv = dis[grow];
                #pragma unroll
                for (int n = 0; n < 8; ++n) {
                    C[(size_t)grow * FD + n * 16 + l16] =
                        (unsigned short)bfr(dv * acc[ms][n][r]);
                }
            }
        }
    }
}

__global__ __launch_bounds__(256) void gemm_mfma_f32(
        const float* __restrict__ A, const unsigned short* __restrict__ WT,
        const float* __restrict__ dis, unsigned short* __restrict__ C, int M) {
    gemm_body<true>(A, WT, dis, C, M);
}

__global__ __launch_bounds__(256) void gemm_mfma_bf16(
        const unsigned short* __restrict__ A, const unsigned short* __restrict__ WT,
        const float* __restrict__ dis, unsigned short* __restrict__ C, int M) {
    gemm_body<false>(A, WT, dis, C, M);
}

// ---------------- CSR aggregation + bias + ReLU ----------------
// Round-0 proven form (48.6 us floor, invariant across 7 designs) — UNCHANGED.

__global__ __launch_bounds__(256) void agg_kernel(
        const unsigned* __restrict__ h, const float* __restrict__ dis,
        const int* __restrict__ rp, const int* __restrict__ col,
        const float2* __restrict__ bias, void* __restrict__ out, int N, int obf) {
    int v = blockIdx.x * 4 + threadIdx.y;          // blockDim = (64, 4): wave per node
    v = __builtin_amdgcn_readfirstlane(v);         // wave-uniform -> scalar rp/col loads
    if (v >= N) return;
    int t = threadIdx.x;                           // 0..63
    float dv = dis[v];
    size_t vb = (size_t)v * 64 + t;
    unsigned hp = h[vb];                           // self term h'[v]
    float2 acc;
    acc.x = uplo(hp); acc.y = uphi(hp);
    int e = rp[v];
    int end = rp[v + 1];

    for (; e + 16 <= end; e += 16) {
        int u[16];
        #pragma unroll
        for (int j = 0; j < 16; ++j) u[j] = col[e + j];   // wave-uniform scalar loads
        unsigned p[16];
        #pragma unroll
        for (int j = 0; j < 16; ++j) p[j] = h[(size_t)u[j] * 64 + t];
        #pragma unroll
        for (int j = 0; j < 16; ++j) {
            acc.x += uplo(p[j]); acc.y += uphi(p[j]);
        }
    }
    for (; e + 4 <= end; e += 4) {
        int u0 = col[e], u1 = col[e + 1], u2 = col[e + 2], u3 = col[e + 3];
        unsigned p0 = h[(size_t)u0 * 64 + t];
        unsigned p1 = h[(size_t)u1 * 64 + t];
        unsigned p2 = h[(size_t)u2 * 64 + t];
        unsigned p3 = h[(size_t)u3 * 64 + t];
        acc.x += uplo(p0); acc.y += uphi(p0);
        acc.x += uplo(p1); acc.y += uphi(p1);
        acc.x += uplo(p2); acc.y += uphi(p2);
        acc.x += uplo(p3); acc.y += uphi(p3);
    }
    for (; e < end; ++e) {
        unsigned p = h[(size_t)col[e] * 64 + t];
        acc.x += uplo(p); acc.y += uphi(p);
    }

    float2 bb = bias[t];
    float2 r;
    r.x = fmaxf(fmaf(dv, acc.x, bb.x), 0.0f);
    r.y = fmaxf(fmaf(dv, acc.y, bb.y), 0.0f);
    if (obf) {
        ((unsigned*)out)[vb] = bfr(r.x) | (bfr(r.y) << 16);
    } else {
        ((float2*)out)[vb] = r;
    }
}

// ---------------- launch ----------------

extern "C" void kernel_launch(void* const* d_in, const int* in_sizes, int n_in,
                              void* d_out, int out_size, void* d_ws, size_t ws_size,
                              hipStream_t stream) {
    const float* x  = (const float*)d_in[0];
    const int*   ei = (const int*)d_in[1];   // [2, E] int32
    const float* W1 = (const float*)d_in[2];
    const float* b1 = (const float*)d_in[3];
    const float* W2 = (const float*)d_in[4];
    const float* b2 = (const float*)d_in[5];

    int N = in_sizes[0] / FD;
    int E = in_sizes[1] / 2;
    const int* src = ei;
    const int* dst = ei + E;
    int K = (N + (1 << BSH) - 1) >> BSH;     // buckets (<= 512 assumed)
    int PB = (E + CH - 1) / CH;              // partition blocks

    char* base = (char*)d_ws;
    size_t off = 0;
    auto align256 = [](size_t v) { return (v + 255) & ~(size_t)255; };
    int*            rp    = (int*)(base + off);            off += align256((size_t)(N + 1) * 4);
    float*          dis   = (float*)(base + off);          off += align256((size_t)N * 4);
    int*            total = (int*)(base + off);            off += align256(512 * 4);
    int*            bbase = (int*)(base + off);            off += align256(513 * 4);
    unsigned short* w1t   = (unsigned short*)(base + off); off += align256((size_t)FD * FD * 2);
    unsigned short* w2t   = (unsigned short*)(base + off); off += align256((size_t)FD * FD * 2);
    int*            col   = (int*)(base + off);            off += align256((size_t)E * 4);
    unsigned short* hbuf  = (unsigned short*)(base + off); off += align256((size_t)N * FD * 2);
    unsigned short* z1    = (unsigned short*)(base + off); off += align256((size_t)N * FD * 2);
    int*            pairs = (int*)(base + off);            off += align256((size_t)E * 4);
    int*            lstartG = (int*)hbuf;   // overlay: dead until gemm1 writes hbuf
    int*            lstartT = (int*)z1;     // overlay: dead until agg1 writes z1
    (void)ws_size; (void)n_in; (void)out_size;

    (void)hipMemsetAsync(total, 0, 512 * 4, stream);
    partition_kernel<<<PB, 256, 0, stream>>>(src, dst, lstartG, total, pairs, E, K);
    int nbx = (K + 1 + 31) / 32;
    int nby = (PB + 31) / 32;
    trtot_kernel<<<nbx * nby + 1, 512, 0, stream>>>(lstartG, lstartT, PB, K + 1,
                                                    total, bbase, rp, K, E, N, nbx);
    build_kernel<<<K + 64, 256, 0, stream>>>(pairs, lstartT, bbase, rp, dis, col,
                                             N, PB, K, W1, w1t, W2, w2t);

    dim3 aggBlk(64, 4);
    int aggGrid = (N + 3) / 4;
    int gemmGrid = (N + 127) / 128;

    gemm_mfma_f32 <<<gemmGrid, 256, 0, stream>>>(x, w1t, dis, hbuf, N);
    agg_kernel<<<aggGrid, aggBlk, 0, stream>>>((const unsigned*)hbuf, dis, rp, col,
                                               (const float2*)b1, z1, N, 1);
    gemm_mfma_bf16<<<gemmGrid, 256, 0, stream>>>(z1, w2t, dis, hbuf, N);
    agg_kernel<<<aggGrid, aggBlk, 0, stream>>>((const unsigned*)hbuf, dis, rp, col,
                                               (const float2*)b2, d_out, N, 0);
}